// Round 5
// baseline (6701.658 us; speedup 1.0000x reference)
//
#include <hip/hip_runtime.h>
#include <stdint.h>

#define NPER 8192
#define NB 4
#define MPER 4096
#define MTOT (NB*MPER)      // 16384
#define KNB 64
#define CIN 64
#define R2C 0.04f           // f32-nearest of python 0.2*0.2 (NOT 0.2f*0.2f!)

// d_out (floats): x_out [MTOT*128] | pos_out [MTOT*3] | batch_out [MTOT]
#define POSOUT_OFF (MTOT*128)
#define BATCH_OFF  (MTOT*128 + MTOT*3)

// ws: nbr u16 [MTOT*64] @0 (2MB) | cnt i32 [MTOT] @2MB (64KB)
// fps scratch: first 512 KB of the x_out region of d_out (float4[8192] per
// cloud: x,y,z,origidx sorted by Morton cell) -- k_conv overwrites later.

// ---------------------------------------------------------------- K1: FPS
// Exact lazy FPS, fixed-path optimized. 512 thr (8 waves), 16 pts/thread,
// Morton-sorted so each thread's points are compact; AABB per thread.
// Per iter (ONE barrier):
//   coords of winner: single float4 L2 load scr[sorted_idx]
//   AABB bound lb; skip exact-provable no-op updates (margin 1.2e-4 >>
//   cumulative 4e-7 f32 rounding); update arithmetic bitwise-numpy
//   key = (d2bits<<26)|(rev_orig<<13)|sorted : u64 max == np.argmax
//     (max d2, tie -> min orig idx; sorted bits only split identical points)
//   6-level wave shfl max -> plain write wslot[m&1][wave] -> barrier ->
//   all lanes read 8 slots, max -> winner sorted idx. No atomics, no resets.
#define FPS_T 512
#define PTS 16
#define NCELL 512

__device__ inline unsigned morton3(unsigned ix, unsigned iy, unsigned iz) {
  unsigned m = 0;
#pragma unroll
  for (int b = 0; b < 3; ++b)
    m |= (((ix >> b) & 1u) << (3*b + 2)) | (((iy >> b) & 1u) << (3*b + 1)) |
         (((iz >> b) & 1u) << (3*b));
  return m;
}

__global__ __launch_bounds__(512, 1) void k_fps(const float* __restrict__ pos,
                                                float* __restrict__ dout)
{
  const int b = blockIdx.x;
  const int tid = threadIdx.x;
  const float* pb = pos + (size_t)b * NPER * 3;
  float* qo = dout + POSOUT_OFF + (size_t)b * MPER * 3;
  float4* scr = (float4*)(dout + (size_t)b * (NPER * 4));   // 128 KB/cloud

  __shared__ unsigned long long wslot[2][8];
  __shared__ unsigned hist[NCELL];
  __shared__ unsigned scanb[NCELL];
  __shared__ unsigned sid0;
  __shared__ __align__(16) float qbuf[MPER*3];   // 48 KB centroid buffer

  hist[tid] = 0u;
  __syncthreads();

  // ---- sort pass 1: count ----
  float sxv[PTS], syv[PTS], szv[PTS];
  unsigned cellv[PTS];
#pragma unroll
  for (int k = 0; k < PTS; ++k) {
    int i = k * FPS_T + tid;
    sxv[k] = pb[i*3+0]; syv[k] = pb[i*3+1]; szv[k] = pb[i*3+2];
    unsigned ix = min(7u, (unsigned)(int)(sxv[k] * 8.0f));
    unsigned iy = min(7u, (unsigned)(int)(syv[k] * 8.0f));
    unsigned iz = min(7u, (unsigned)(int)(szv[k] * 8.0f));
    cellv[k] = morton3(ix, iy, iz);
    atomicAdd(&hist[cellv[k]], 1u);
  }
  __syncthreads();
  // ---- inclusive scan -> exclusive starts ----
  scanb[tid] = hist[tid];
  __syncthreads();
  for (int s = 1; s < NCELL; s <<= 1) {
    unsigned v = (tid >= s) ? scanb[tid - s] : 0u;
    __syncthreads();
    if (tid >= s) scanb[tid] += v;
    __syncthreads();
  }
  hist[tid] = scanb[tid] - hist[tid];   // exclusive start per cell
  __syncthreads();
  // ---- sort pass 2: scatter (x,y,z,origidx) ----
#pragma unroll
  for (int k = 0; k < PTS; ++k) {
    unsigned dst = atomicAdd(&hist[cellv[k]], 1u);
    int orig = k * FPS_T + tid;
    float4 v;
    v.x = sxv[k]; v.y = syv[k]; v.z = szv[k];
    v.w = __uint_as_float((unsigned)orig);
    scr[dst] = v;
    if (orig == 0) sid0 = dst;          // sorted position of seed point
  }
  __threadfence();
  __syncthreads();
  // ---- load my 16 contiguous sorted points + AABB ----
  float X[PTS], Y[PTS], Z[PTS], D[PTS];
  unsigned RK[PTS];
  float bxlo = 3.402823466e+38f, bylo = bxlo, bzlo = bxlo;
  float bxhi = -bxlo, byhi = bxhi, bzhi = bxhi;
#pragma unroll
  for (int k = 0; k < PTS; ++k) {
    float4 v = scr[tid * PTS + k];
    X[k] = v.x; Y[k] = v.y; Z[k] = v.z;
    unsigned orig = __float_as_uint(v.w);
    RK[k] = ((unsigned)(NPER - 1 - orig) << 13) | (unsigned)(tid * PTS + k);
    D[k] = 3.402823466e+38f;
    bxlo = fminf(bxlo, v.x); bxhi = fmaxf(bxhi, v.x);
    bylo = fminf(bylo, v.y); byhi = fmaxf(byhi, v.y);
    bzlo = fminf(bzlo, v.z); bzhi = fmaxf(bzhi, v.z);
  }

  // ---- main loop ----
  unsigned long long tkey = 0ull, wkey = 0ull;
  float lmax = 3.402823466e+38f;
  unsigned sidx = sid0;
  const int wv = tid >> 6;
  for (int m = 1; m < MPER; ++m) {
    const float4 c = scr[sidx];         // winner coords: one L2 float4
    if (tid == 0) {                     // record row m-1
      qbuf[(m-1)*3+0] = c.x; qbuf[(m-1)*3+1] = c.y; qbuf[(m-1)*3+2] = c.z;
    }
    float ax = fmaxf(fmaxf(__fsub_rn(bxlo, c.x), __fsub_rn(c.x, bxhi)), 0.0f);
    float ay = fmaxf(fmaxf(__fsub_rn(bylo, c.y), __fsub_rn(c.y, byhi)), 0.0f);
    float az = fmaxf(fmaxf(__fsub_rn(bzlo, c.z), __fsub_rn(c.z, bzhi)), 0.0f);
    float lb = ax*ax + ay*ay + az*az;
    bool upd = (lb * 0.99988f) < lmax;  // margin >> rounding: skip is exact
    if (__ballot(upd) != 0ull) {
      if (upd) {
        unsigned long long bk = 0ull;
#pragma unroll
        for (int k = 0; k < PTS; ++k) {
          float dx = __fsub_rn(X[k], c.x);
          float dy = __fsub_rn(Y[k], c.y);
          float dz = __fsub_rn(Z[k], c.z);
          float s = __fadd_rn(__fadd_rn(__fmul_rn(dx,dx), __fmul_rn(dy,dy)),
                              __fmul_rn(dz,dz));
          float dn = fminf(D[k], s);
          D[k] = dn;
          unsigned long long kk =
            ((unsigned long long)__float_as_uint(dn) << 26) | RK[k];
          bk = (kk > bk) ? kk : bk;
        }
        tkey = bk;
        lmax = __uint_as_float((unsigned)(bk >> 26));
      }
      unsigned long long pkk = tkey;
#pragma unroll
      for (int off = 1; off < 64; off <<= 1) {
        unsigned long long o = __shfl_xor(pkk, off);
        pkk = (o > pkk) ? o : pkk;
      }
      wkey = pkk;
    }
    if ((tid & 63) == 0) wslot[m & 1][wv] = wkey;
    __syncthreads();
    unsigned long long k0 = wslot[m & 1][0], k1 = wslot[m & 1][1];
    unsigned long long k2 = wslot[m & 1][2], k3 = wslot[m & 1][3];
    unsigned long long k4 = wslot[m & 1][4], k5 = wslot[m & 1][5];
    unsigned long long k6 = wslot[m & 1][6], k7 = wslot[m & 1][7];
    k0 = (k1 > k0) ? k1 : k0;  k2 = (k3 > k2) ? k3 : k2;
    k4 = (k5 > k4) ? k5 : k4;  k6 = (k7 > k6) ? k7 : k6;
    k0 = (k2 > k0) ? k2 : k0;  k4 = (k6 > k4) ? k6 : k4;
    k0 = (k4 > k0) ? k4 : k0;
    sidx = (unsigned)(k0 & 0x1FFFull);
  }
  {                                     // final selection (m = MPER-1)
    const float4 c = scr[sidx];
    if (tid == 0) {
      qbuf[(MPER-1)*3+0] = c.x; qbuf[(MPER-1)*3+1] = c.y; qbuf[(MPER-1)*3+2] = c.z;
    }
  }
  __syncthreads();
  for (int e = tid; e < MPER*3/4; e += FPS_T)
    ((float4*)qo)[e] = ((const float4*)qbuf)[e];
}

// ------------------------------------------------- K2: radius + top-K select
// One wave per centroid. Candidates (d2<=R2) appended via ballot-prefix into
// LDS as u64 key = (d2_bits<<32)|idx (d2>=0 so float bits are order-monotone;
// idx in low bits reproduces top_k's lower-index tie-break). Bitonic sort 512.
#define SCAP 512
__global__ __launch_bounds__(256) void k_radius(const float* __restrict__ pos,
    float* __restrict__ dout, unsigned short* __restrict__ nbr,
    int* __restrict__ cnt)
{
  __shared__ unsigned long long cand[4][SCAP];
  const int wid = threadIdx.x >> 6, lane = threadIdx.x & 63;
  const int m = blockIdx.x * 4 + wid;
  const int b = m >> 12;
  const float* pb = pos + (size_t)b * NPER * 3;
  const float* q = dout + POSOUT_OFF + (size_t)m * 3;
  const float qx = q[0], qy = q[1], qz = q[2];
  unsigned cw = 0;
  for (int it = 0; it < NPER/64; ++it) {
    int i = (it << 6) + lane;
    float dx = __fsub_rn(qx, pb[i*3+0]);
    float dy = __fsub_rn(qy, pb[i*3+1]);
    float dz = __fsub_rn(qz, pb[i*3+2]);
    float d2 = __fadd_rn(__fadd_rn(__fmul_rn(dx,dx), __fmul_rn(dy,dy)),
                         __fmul_rn(dz,dz));
    bool in = (d2 <= R2C);
    unsigned long long mk = __ballot(in);
    unsigned pre = (unsigned)__popcll(mk & ((1ull << lane) - 1ull));
    if (in) {
      unsigned slot = cw + pre;
      if (slot < SCAP)
        cand[wid][slot] =
          (((unsigned long long)__float_as_uint(d2)) << 32) | (unsigned)i;
    }
    cw += (unsigned)__popcll(mk);
  }
  if (cw > SCAP) cw = SCAP;   // statistically unreachable (lambda_max ~274)
  for (int s = (int)cw + lane; s < SCAP; s += 64) cand[wid][s] = ~0ull;
  __syncthreads();
  for (int k = 2; k <= SCAP; k <<= 1) {
    for (int j = k >> 1; j > 0; j >>= 1) {
#pragma unroll
      for (int s = 0; s < SCAP/128; ++s) {
        int t = lane + (s << 6);
        int e = ((t & ~(j-1)) << 1) | (t & (j-1));
        int p = e | j;
        unsigned long long a = cand[wid][e], c = cand[wid][p];
        bool asc = ((e & k) == 0);
        bool sw = asc ? (a > c) : (a < c);
        if (sw) { cand[wid][e] = c; cand[wid][p] = a; }
      }
      __syncthreads();
    }
  }
  int kk = (int)cw; if (kk > KNB) kk = KNB;
  unsigned long long key = cand[wid][lane];
  nbr[(size_t)m*KNB + lane] =
    (lane < kk) ? (unsigned short)(key & 0xFFFFull) : (unsigned short)0;
  if (lane == 0) {
    cnt[m] = kk;
    dout[BATCH_OFF + m] = (float)b;   // batch_out (buffer read as f32)
  }
}

// --------------------------------------------- K3: gather -> MLP -> max (fp32)
// One 128-thr block per centroid. featT[ch][j] (stride 68) + W1 in LDS;
// stage B: 8j x 4h register tile; h1T reuses featT buffer; W2 streamed in
// 16-row chunks through the W1 buffer; stage C: 8j x 8c tile; masked
// shuffle-max over j, write 128 outputs.
__global__ __launch_bounds__(128) void k_conv(
    const float* __restrict__ x, const float* __restrict__ pos,
    const float* __restrict__ W1, const float* __restrict__ b1,
    const float* __restrict__ W2, const float* __restrict__ b2,
    const unsigned short* __restrict__ nbr, const int* __restrict__ cntp,
    float* __restrict__ dout)
{
  __shared__ __align__(16) float bufA[68*68];   // featT then h1T (stride 68)
  __shared__ __align__(16) float bufB[68*68];   // W1 then W2 chunks (str 136)
  __shared__ unsigned short nbr_s[64];
  __shared__ float qv[3];
  __shared__ int cnt_s;
  const int t = threadIdx.x;
  const int m = blockIdx.x;
  const int b = m >> 12;
  if (t < 64) nbr_s[t] = nbr[(size_t)m*KNB + t];
  else if (t == 64) cnt_s = cntp[m];
  else if (t >= 65 && t < 68) qv[t-65] = dout[POSOUT_OFF + (size_t)m*3 + (t-65)];
  for (int e = t; e < 67*64; e += 128) {
    int ch = e >> 6, h = e & 63;
    bufB[ch*68 + h] = W1[e];
  }
  __syncthreads();
  {                                   // gather x rows -> featT rows 0..63
    const int ch = t & 63, jj = t >> 6;
    const size_t xb = (size_t)b * NPER * CIN;
    for (int j0 = 0; j0 < 64; j0 += 2) {
      int j = j0 + jj;
      int r = nbr_s[j];
      bufA[ch*68 + j] = x[xb + (size_t)r*CIN + ch];
    }
  }
  {                                   // rel -> rows 64..66
    const size_t pbb = (size_t)b * NPER * 3;
    for (int e = t; e < 192; e += 128) {
      int j = e & 63, d = e >> 6;
      int r = nbr_s[j];
      bufA[(64+d)*68 + j] = pos[pbb + (size_t)r*3 + d] - qv[d];
    }
  }
  __syncthreads();

  const int jg = t & 7, hg = t >> 3;
  const int j0 = jg << 3;
  const int h0 = hg << 2;
  float acc[4][8];
#pragma unroll
  for (int hh = 0; hh < 4; ++hh)
#pragma unroll
    for (int j = 0; j < 8; ++j) acc[hh][j] = 0.0f;
  for (int ch = 0; ch < 67; ++ch) {
    const float4 fa = *(const float4*)&bufA[ch*68 + j0];
    const float4 fb = *(const float4*)&bufA[ch*68 + j0 + 4];
    const float4 w  = *(const float4*)&bufB[ch*68 + h0];
    const float ws4[4] = {w.x, w.y, w.z, w.w};
    const float fj[8] = {fa.x, fa.y, fa.z, fa.w, fb.x, fb.y, fb.z, fb.w};
#pragma unroll
    for (int hh = 0; hh < 4; ++hh)
#pragma unroll
      for (int j = 0; j < 8; ++j)
        acc[hh][j] += ws4[hh] * fj[j];
  }
  __syncthreads();                    // featT + W1 reads complete
  {                                   // h1T = relu(acc + b1) into bufA
    const float4 bb = *(const float4*)&b1[h0];
    const float bv[4] = {bb.x, bb.y, bb.z, bb.w};
#pragma unroll
    for (int hh = 0; hh < 4; ++hh) {
      float4 o0, o1;
      o0.x = fmaxf(acc[hh][0] + bv[hh], 0.0f);
      o0.y = fmaxf(acc[hh][1] + bv[hh], 0.0f);
      o0.z = fmaxf(acc[hh][2] + bv[hh], 0.0f);
      o0.w = fmaxf(acc[hh][3] + bv[hh], 0.0f);
      o1.x = fmaxf(acc[hh][4] + bv[hh], 0.0f);
      o1.y = fmaxf(acc[hh][5] + bv[hh], 0.0f);
      o1.z = fmaxf(acc[hh][6] + bv[hh], 0.0f);
      o1.w = fmaxf(acc[hh][7] + bv[hh], 0.0f);
      *(float4*)&bufA[(h0+hh)*68 + j0] = o0;
      *(float4*)&bufA[(h0+hh)*68 + j0 + 4] = o1;
    }
  }
  const int c0 = hg << 3;             // stage C: 8j x 8c
  float acc2[8][8];                   // [c][j]
#pragma unroll
  for (int c = 0; c < 8; ++c)
#pragma unroll
    for (int j = 0; j < 8; ++j) acc2[c][j] = 0.0f;
  for (int hc = 0; hc < 64; hc += 16) {
    __syncthreads();                  // h1T ready / prior chunk consumed
    for (int e = t; e < 16*128; e += 128) {
      int hh = e >> 7, c = e & 127;
      bufB[hh*136 + c] = W2[(size_t)(hc+hh)*128 + c];
    }
    __syncthreads();
#pragma unroll
    for (int h = 0; h < 16; ++h) {
      const float4 ja = *(const float4*)&bufA[(hc+h)*68 + j0];
      const float4 jb = *(const float4*)&bufA[(hc+h)*68 + j0 + 4];
      const float4 wa = *(const float4*)&bufB[h*136 + c0];
      const float4 wb = *(const float4*)&bufB[h*136 + c0 + 4];
      const float hv[8] = {ja.x, ja.y, ja.z, ja.w, jb.x, jb.y, jb.z, jb.w};
      const float wv[8] = {wa.x, wa.y, wa.z, wa.w, wb.x, wb.y, wb.z, wb.w};
#pragma unroll
      for (int c = 0; c < 8; ++c)
#pragma unroll
        for (int j = 0; j < 8; ++j)
          acc2[c][j] += wv[c] * hv[j];
    }
  }
  const int cntv = cnt_s;
  const float4 b2a = *(const float4*)&b2[c0];
  const float4 b2b = *(const float4*)&b2[c0 + 4];
  const float bv2[8] = {b2a.x, b2a.y, b2a.z, b2a.w, b2b.x, b2b.y, b2b.z, b2b.w};
  float best[8];
#pragma unroll
  for (int c = 0; c < 8; ++c) {
    float v = -3.402823466e+38f;
#pragma unroll
    for (int j = 0; j < 8; ++j) {
      float hv = fmaxf(acc2[c][j] + bv2[c], 0.0f);
      v = (j0 + j < cntv) ? fmaxf(v, hv) : v;
    }
    best[c] = v;
  }
#pragma unroll
  for (int off = 1; off < 8; off <<= 1)
#pragma unroll
    for (int c = 0; c < 8; ++c)
      best[c] = fmaxf(best[c], __shfl_xor(best[c], off));
  if (jg == 0) {
    float4 o0 = {best[0], best[1], best[2], best[3]};
    float4 o1 = {best[4], best[5], best[6], best[7]};
    *(float4*)&dout[(size_t)m*128 + c0] = o0;
    *(float4*)&dout[(size_t)m*128 + c0 + 4] = o1;
  }
}

extern "C" void kernel_launch(void* const* d_in, const int* in_sizes, int n_in,
                              void* d_out, int out_size, void* d_ws, size_t ws_size,
                              hipStream_t stream) {
  const float* x   = (const float*)d_in[0];
  const float* pos = (const float*)d_in[1];
  // d_in[2] = batch (layout known statically, unused)
  const float* W1  = (const float*)d_in[3];
  const float* b1  = (const float*)d_in[4];
  const float* W2  = (const float*)d_in[5];
  const float* b2  = (const float*)d_in[6];
  float* dout = (float*)d_out;
  unsigned short* nbr = (unsigned short*)d_ws;
  int* cnt = (int*)((char*)d_ws + (size_t)MTOT*KNB*2);

  hipLaunchKernelGGL(k_fps,    dim3(NB),     dim3(FPS_T), 0, stream, pos, dout);
  hipLaunchKernelGGL(k_radius, dim3(MTOT/4), dim3(256),   0, stream, pos, dout, nbr, cnt);
  hipLaunchKernelGGL(k_conv,   dim3(MTOT),   dim3(128),   0, stream,
                     x, pos, W1, b1, W2, b2, nbr, cnt, dout);
}

// Round 6
// 3593.961 us; speedup vs baseline: 1.8647x; 1.8647x over previous
//
#include <hip/hip_runtime.h>
#include <stdint.h>

#define NPER 8192
#define NB 4
#define MPER 4096
#define MTOT (NB*MPER)      // 16384
#define KNB 64
#define CIN 64
#define R2C 0.04f           // f32-nearest of python 0.2*0.2 (NOT 0.2f*0.2f!)

// d_out (floats): x_out [MTOT*128] | pos_out [MTOT*3] | batch_out [MTOT]
#define POSOUT_OFF (MTOT*128)
#define BATCH_OFF  (MTOT*128 + MTOT*3)

// ws: nbr u16 [MTOT*64] @0 (2MB) | cnt i32 [MTOT] @2MB (64KB)
// fps scratch: first 512 KB of the x_out region of d_out (float4[8192] per
// cloud: x,y,z,origidx sorted by Morton cell) -- k_conv overwrites later.

// ---------------------------------------------------------------- K1: FPS
// Exact lazy FPS (R4 skeleton) with DPP wave reduction replacing the
// 6-level u64 shfl chain (~700 cyc -> ~60 cyc).
// 1024 thr (16 waves, 4/SIMD), 8 pts/thread Morton-sorted, AABB prune
// (skip is provably exact: margin 1.2e-4 >> 5e-7 rounding). Update
// arithmetic bitwise-numpy: ((dx*dx+dy*dy)+dz*dz), rn, no fma.
// Key = (d2bits<<26)|(rev_orig<<13)|sorted: u64 max == np.argmax first-max.
// Cross-lane: M = dpp_max(d2bits); rk-min via dpp_max(~rk masked to hi==M);
// readlane(63) broadcasts as SGPR. One u64 LDS atomicMax per wave into
// 3-phase slot, ONE barrier/iter; winner coords = one float4 L1 load.
#define FPS_T 1024
#define PTS 8
#define NCELL 512

__device__ inline unsigned morton3(unsigned ix, unsigned iy, unsigned iz) {
  unsigned m = 0;
#pragma unroll
  for (int b = 0; b < 3; ++b)
    m |= (((ix >> b) & 1u) << (3*b + 2)) | (((iy >> b) & 1u) << (3*b + 1)) |
         (((iz >> b) & 1u) << (3*b));
  return m;
}

template<int CTRL>
__device__ __forceinline__ unsigned dppmax(unsigned v) {
  unsigned t = (unsigned)__builtin_amdgcn_update_dpp(
      0, (int)v, CTRL, 0xf, 0xf, true);   // bound_ctrl: OOB lanes read 0
  return v > t ? v : t;
}
// max over all 64 lanes, result broadcast via SGPR. Identity is 0 (all our
// reduced quantities are >= 0 and < 2^31).
__device__ __forceinline__ unsigned wave_max_u32(unsigned v) {
  v = dppmax<0x111>(v);   // row_shr:1
  v = dppmax<0x112>(v);   // row_shr:2
  v = dppmax<0x114>(v);   // row_shr:4
  v = dppmax<0x118>(v);   // row_shr:8   -> lane15 of each row16 has row max
  v = dppmax<0x142>(v);   // row_bcast15 -> lane31/63 have 32-half maxes
  v = dppmax<0x143>(v);   // row_bcast31 -> lane63 has full-wave max
  return (unsigned)__builtin_amdgcn_readlane((int)v, 63);
}

__global__ __launch_bounds__(1024, 4) void k_fps(const float* __restrict__ pos,
                                                 float* __restrict__ dout)
{
  const int b = blockIdx.x;
  const int tid = threadIdx.x;
  const float* pb = pos + (size_t)b * NPER * 3;
  float* qo = dout + POSOUT_OFF + (size_t)b * MPER * 3;
  float4* scr = (float4*)(dout + (size_t)b * (NPER * 4));   // 128 KB/cloud

  __shared__ unsigned long long slot3[3];
  __shared__ unsigned hist[NCELL];
  __shared__ unsigned scanb[NCELL];
  __shared__ unsigned sid0;
  __shared__ __align__(16) float qbuf[MPER*3];   // 48 KB centroid buffer

  if (tid < NCELL) hist[tid] = 0u;
  if (tid == 0) { slot3[0] = 0ull; slot3[1] = 0ull; slot3[2] = 0ull; }
  __syncthreads();

  // ---- sort pass 1: count ----
  float sxv[PTS], syv[PTS], szv[PTS];
  unsigned cellv[PTS];
#pragma unroll
  for (int k = 0; k < PTS; ++k) {
    int i = k * FPS_T + tid;
    sxv[k] = pb[i*3+0]; syv[k] = pb[i*3+1]; szv[k] = pb[i*3+2];
    unsigned ix = min(7u, (unsigned)(int)(sxv[k] * 8.0f));
    unsigned iy = min(7u, (unsigned)(int)(syv[k] * 8.0f));
    unsigned iz = min(7u, (unsigned)(int)(szv[k] * 8.0f));
    cellv[k] = morton3(ix, iy, iz);
    atomicAdd(&hist[cellv[k]], 1u);
  }
  __syncthreads();
  // ---- inclusive scan -> exclusive starts ----
  if (tid < NCELL) scanb[tid] = hist[tid];
  __syncthreads();
  for (int s = 1; s < NCELL; s <<= 1) {
    unsigned v = 0u;
    if (tid >= s && tid < NCELL) v = scanb[tid - s];
    __syncthreads();
    if (tid >= s && tid < NCELL) scanb[tid] += v;
    __syncthreads();
  }
  if (tid < NCELL) hist[tid] = scanb[tid] - hist[tid];
  __syncthreads();
  // ---- sort pass 2: scatter (x,y,z,origidx) ----
#pragma unroll
  for (int k = 0; k < PTS; ++k) {
    unsigned dst = atomicAdd(&hist[cellv[k]], 1u);
    int orig = k * FPS_T + tid;
    float4 v;
    v.x = sxv[k]; v.y = syv[k]; v.z = szv[k];
    v.w = __uint_as_float((unsigned)orig);
    scr[dst] = v;
    if (orig == 0) sid0 = dst;          // sorted position of seed point
  }
  __threadfence();
  __syncthreads();
  // ---- load my 8 contiguous sorted points + AABB ----
  float X[PTS], Y[PTS], Z[PTS], D[PTS];
  unsigned RK[PTS];
  float bxlo = 3.402823466e+38f, bylo = bxlo, bzlo = bxlo;
  float bxhi = -bxlo, byhi = bxhi, bzhi = bxhi;
#pragma unroll
  for (int k = 0; k < PTS; ++k) {
    float4 v = scr[tid * PTS + k];
    X[k] = v.x; Y[k] = v.y; Z[k] = v.z;
    unsigned orig = __float_as_uint(v.w);
    RK[k] = ((unsigned)(NPER - 1 - orig) << 13) | (unsigned)(tid * PTS + k);
    D[k] = 3.402823466e+38f;
    bxlo = fminf(bxlo, v.x); bxhi = fmaxf(bxhi, v.x);
    bylo = fminf(bylo, v.y); byhi = fmaxf(byhi, v.y);
    bzlo = fminf(bzlo, v.z); bzhi = fmaxf(bzhi, v.z);
  }

  // ---- main loop ----
  unsigned long long tkey = 0ull, wkey = 0ull;
  float lmax = 3.402823466e+38f;
  unsigned sidx = sid0;
  for (int m = 1; m < MPER; ++m) {
    const float4 c = scr[sidx];         // winner coords: one L1/L2 float4
    if (tid == 0) {                     // record row m-1
      qbuf[(m-1)*3+0] = c.x; qbuf[(m-1)*3+1] = c.y; qbuf[(m-1)*3+2] = c.z;
    }
    if (tid == 1) slot3[(m+1) % 3] = 0ull;   // phase-safe future reset
    float ax = fmaxf(fmaxf(__fsub_rn(bxlo, c.x), __fsub_rn(c.x, bxhi)), 0.0f);
    float ay = fmaxf(fmaxf(__fsub_rn(bylo, c.y), __fsub_rn(c.y, byhi)), 0.0f);
    float az = fmaxf(fmaxf(__fsub_rn(bzlo, c.z), __fsub_rn(c.z, bzhi)), 0.0f);
    float lb = ax*ax + ay*ay + az*az;
    bool upd = (lb * 0.99988f) < lmax;  // margin >> rounding: skip is exact
    if (__ballot(upd) != 0ull) {        // wave-uniform; exec stays full
      if (upd) {
        unsigned long long bk = 0ull;
#pragma unroll
        for (int k = 0; k < PTS; ++k) {
          float dx = __fsub_rn(X[k], c.x);
          float dy = __fsub_rn(Y[k], c.y);
          float dz = __fsub_rn(Z[k], c.z);
          float s = __fadd_rn(__fadd_rn(__fmul_rn(dx,dx), __fmul_rn(dy,dy)),
                              __fmul_rn(dz,dz));
          float dn = fminf(D[k], s);
          D[k] = dn;
          unsigned long long kk =
            ((unsigned long long)__float_as_uint(dn) << 26) | RK[k];
          bk = (kk > bk) ? kk : bk;
        }
        tkey = bk;
        lmax = __uint_as_float((unsigned)(bk >> 26));
      }
      // exact u64-max via two u32 DPP reduces:
      unsigned hi = (unsigned)(tkey >> 26);          // d2 bits (max wins)
      unsigned M = wave_max_u32(hi);
      unsigned rk = (unsigned)tkey & 0x3FFFFFFu;     // tie: min rk
      unsigned cand = (hi == M) ? (~rk & 0x3FFFFFFu) : 0u;
      unsigned C = wave_max_u32(cand);
      wkey = ((unsigned long long)M << 26) | (~C & 0x3FFFFFFu);
    }
    if ((tid & 63) == 0) atomicMax(&slot3[m % 3], wkey);
    __syncthreads();
    sidx = (unsigned)(slot3[m % 3] & 0x1FFFull);
  }
  {                                     // final selection (m = MPER-1)
    const float4 c = scr[sidx];
    if (tid == 0) {
      qbuf[(MPER-1)*3+0] = c.x; qbuf[(MPER-1)*3+1] = c.y; qbuf[(MPER-1)*3+2] = c.z;
    }
  }
  __syncthreads();
  for (int e = tid; e < MPER*3/4; e += FPS_T)
    ((float4*)qo)[e] = ((const float4*)qbuf)[e];
}

// ------------------------------------------------- K2: radius + top-K select
// One wave per centroid. Candidates (d2<=R2) appended via ballot-prefix into
// LDS as u64 key = (d2_bits<<32)|idx (d2>=0 so float bits are order-monotone;
// idx in low bits reproduces top_k's lower-index tie-break). Bitonic sort 512.
#define SCAP 512
__global__ __launch_bounds__(256) void k_radius(const float* __restrict__ pos,
    float* __restrict__ dout, unsigned short* __restrict__ nbr,
    int* __restrict__ cnt)
{
  __shared__ unsigned long long cand[4][SCAP];
  const int wid = threadIdx.x >> 6, lane = threadIdx.x & 63;
  const int m = blockIdx.x * 4 + wid;
  const int b = m >> 12;
  const float* pb = pos + (size_t)b * NPER * 3;
  const float* q = dout + POSOUT_OFF + (size_t)m * 3;
  const float qx = q[0], qy = q[1], qz = q[2];
  unsigned cw = 0;
  for (int it = 0; it < NPER/64; ++it) {
    int i = (it << 6) + lane;
    float dx = __fsub_rn(qx, pb[i*3+0]);
    float dy = __fsub_rn(qy, pb[i*3+1]);
    float dz = __fsub_rn(qz, pb[i*3+2]);
    float d2 = __fadd_rn(__fadd_rn(__fmul_rn(dx,dx), __fmul_rn(dy,dy)),
                         __fmul_rn(dz,dz));
    bool in = (d2 <= R2C);
    unsigned long long mk = __ballot(in);
    unsigned pre = (unsigned)__popcll(mk & ((1ull << lane) - 1ull));
    if (in) {
      unsigned slot = cw + pre;
      if (slot < SCAP)
        cand[wid][slot] =
          (((unsigned long long)__float_as_uint(d2)) << 32) | (unsigned)i;
    }
    cw += (unsigned)__popcll(mk);
  }
  if (cw > SCAP) cw = SCAP;   // statistically unreachable (lambda_max ~274)
  for (int s = (int)cw + lane; s < SCAP; s += 64) cand[wid][s] = ~0ull;
  __syncthreads();
  for (int k = 2; k <= SCAP; k <<= 1) {
    for (int j = k >> 1; j > 0; j >>= 1) {
#pragma unroll
      for (int s = 0; s < SCAP/128; ++s) {
        int t = lane + (s << 6);
        int e = ((t & ~(j-1)) << 1) | (t & (j-1));
        int p = e | j;
        unsigned long long a = cand[wid][e], c = cand[wid][p];
        bool asc = ((e & k) == 0);
        bool sw = asc ? (a > c) : (a < c);
        if (sw) { cand[wid][e] = c; cand[wid][p] = a; }
      }
      __syncthreads();
    }
  }
  int kk = (int)cw; if (kk > KNB) kk = KNB;
  unsigned long long key = cand[wid][lane];
  nbr[(size_t)m*KNB + lane] =
    (lane < kk) ? (unsigned short)(key & 0xFFFFull) : (unsigned short)0;
  if (lane == 0) {
    cnt[m] = kk;
    dout[BATCH_OFF + m] = (float)b;   // batch_out (buffer read as f32)
  }
}

// --------------------------------------------- K3: gather -> MLP -> max (fp32)
// One 128-thr block per centroid. featT[ch][j] (stride 68) + W1 in LDS;
// stage B: 8j x 4h register tile; h1T reuses featT buffer; W2 streamed in
// 16-row chunks through the W1 buffer; stage C: 8j x 8c tile; masked
// shuffle-max over j, write 128 outputs.
__global__ __launch_bounds__(128) void k_conv(
    const float* __restrict__ x, const float* __restrict__ pos,
    const float* __restrict__ W1, const float* __restrict__ b1,
    const float* __restrict__ W2, const float* __restrict__ b2,
    const unsigned short* __restrict__ nbr, const int* __restrict__ cntp,
    float* __restrict__ dout)
{
  __shared__ __align__(16) float bufA[68*68];   // featT then h1T (stride 68)
  __shared__ __align__(16) float bufB[68*68];   // W1 then W2 chunks (str 136)
  __shared__ unsigned short nbr_s[64];
  __shared__ float qv[3];
  __shared__ int cnt_s;
  const int t = threadIdx.x;
  const int m = blockIdx.x;
  const int b = m >> 12;
  if (t < 64) nbr_s[t] = nbr[(size_t)m*KNB + t];
  else if (t == 64) cnt_s = cntp[m];
  else if (t >= 65 && t < 68) qv[t-65] = dout[POSOUT_OFF + (size_t)m*3 + (t-65)];
  for (int e = t; e < 67*64; e += 128) {
    int ch = e >> 6, h = e & 63;
    bufB[ch*68 + h] = W1[e];
  }
  __syncthreads();
  {                                   // gather x rows -> featT rows 0..63
    const int ch = t & 63, jj = t >> 6;
    const size_t xb = (size_t)b * NPER * CIN;
    for (int j0 = 0; j0 < 64; j0 += 2) {
      int j = j0 + jj;
      int r = nbr_s[j];
      bufA[ch*68 + j] = x[xb + (size_t)r*CIN + ch];
    }
  }
  {                                   // rel -> rows 64..66
    const size_t pbb = (size_t)b * NPER * 3;
    for (int e = t; e < 192; e += 128) {
      int j = e & 63, d = e >> 6;
      int r = nbr_s[j];
      bufA[(64+d)*68 + j] = pos[pbb + (size_t)r*3 + d] - qv[d];
    }
  }
  __syncthreads();

  const int jg = t & 7, hg = t >> 3;
  const int j0 = jg << 3;
  const int h0 = hg << 2;
  float acc[4][8];
#pragma unroll
  for (int hh = 0; hh < 4; ++hh)
#pragma unroll
    for (int j = 0; j < 8; ++j) acc[hh][j] = 0.0f;
  for (int ch = 0; ch < 67; ++ch) {
    const float4 fa = *(const float4*)&bufA[ch*68 + j0];
    const float4 fb = *(const float4*)&bufA[ch*68 + j0 + 4];
    const float4 w  = *(const float4*)&bufB[ch*68 + h0];
    const float ws4[4] = {w.x, w.y, w.z, w.w};
    const float fj[8] = {fa.x, fa.y, fa.z, fa.w, fb.x, fb.y, fb.z, fb.w};
#pragma unroll
    for (int hh = 0; hh < 4; ++hh)
#pragma unroll
      for (int j = 0; j < 8; ++j)
        acc[hh][j] += ws4[hh] * fj[j];
  }
  __syncthreads();                    // featT + W1 reads complete
  {                                   // h1T = relu(acc + b1) into bufA
    const float4 bb = *(const float4*)&b1[h0];
    const float bv[4] = {bb.x, bb.y, bb.z, bb.w};
#pragma unroll
    for (int hh = 0; hh < 4; ++hh) {
      float4 o0, o1;
      o0.x = fmaxf(acc[hh][0] + bv[hh], 0.0f);
      o0.y = fmaxf(acc[hh][1] + bv[hh], 0.0f);
      o0.z = fmaxf(acc[hh][2] + bv[hh], 0.0f);
      o0.w = fmaxf(acc[hh][3] + bv[hh], 0.0f);
      o1.x = fmaxf(acc[hh][4] + bv[hh], 0.0f);
      o1.y = fmaxf(acc[hh][5] + bv[hh], 0.0f);
      o1.z = fmaxf(acc[hh][6] + bv[hh], 0.0f);
      o1.w = fmaxf(acc[hh][7] + bv[hh], 0.0f);
      *(float4*)&bufA[(h0+hh)*68 + j0] = o0;
      *(float4*)&bufA[(h0+hh)*68 + j0 + 4] = o1;
    }
  }
  const int c0 = hg << 3;             // stage C: 8j x 8c
  float acc2[8][8];                   // [c][j]
#pragma unroll
  for (int c = 0; c < 8; ++c)
#pragma unroll
    for (int j = 0; j < 8; ++j) acc2[c][j] = 0.0f;
  for (int hc = 0; hc < 64; hc += 16) {
    __syncthreads();                  // h1T ready / prior chunk consumed
    for (int e = t; e < 16*128; e += 128) {
      int hh = e >> 7, c = e & 127;
      bufB[hh*136 + c] = W2[(size_t)(hc+hh)*128 + c];
    }
    __syncthreads();
#pragma unroll
    for (int h = 0; h < 16; ++h) {
      const float4 ja = *(const float4*)&bufA[(hc+h)*68 + j0];
      const float4 jb = *(const float4*)&bufA[(hc+h)*68 + j0 + 4];
      const float4 wa = *(const float4*)&bufB[h*136 + c0];
      const float4 wb = *(const float4*)&bufB[h*136 + c0 + 4];
      const float hv[8] = {ja.x, ja.y, ja.z, ja.w, jb.x, jb.y, jb.z, jb.w};
      const float wv[8] = {wa.x, wa.y, wa.z, wa.w, wb.x, wb.y, wb.z, wb.w};
#pragma unroll
      for (int c = 0; c < 8; ++c)
#pragma unroll
        for (int j = 0; j < 8; ++j)
          acc2[c][j] += wv[c] * hv[j];
    }
  }
  const int cntv = cnt_s;
  const float4 b2a = *(const float4*)&b2[c0];
  const float4 b2b = *(const float4*)&b2[c0 + 4];
  const float bv2[8] = {b2a.x, b2a.y, b2a.z, b2a.w, b2b.x, b2b.y, b2b.z, b2b.w};
  float best[8];
#pragma unroll
  for (int c = 0; c < 8; ++c) {
    float v = -3.402823466e+38f;
#pragma unroll
    for (int j = 0; j < 8; ++j) {
      float hv = fmaxf(acc2[c][j] + bv2[c], 0.0f);
      v = (j0 + j < cntv) ? fmaxf(v, hv) : v;
    }
    best[c] = v;
  }
#pragma unroll
  for (int off = 1; off < 8; off <<= 1)
#pragma unroll
    for (int c = 0; c < 8; ++c)
      best[c] = fmaxf(best[c], __shfl_xor(best[c], off));
  if (jg == 0) {
    float4 o0 = {best[0], best[1], best[2], best[3]};
    float4 o1 = {best[4], best[5], best[6], best[7]};
    *(float4*)&dout[(size_t)m*128 + c0] = o0;
    *(float4*)&dout[(size_t)m*128 + c0 + 4] = o1;
  }
}

extern "C" void kernel_launch(void* const* d_in, const int* in_sizes, int n_in,
                              void* d_out, int out_size, void* d_ws, size_t ws_size,
                              hipStream_t stream) {
  const float* x   = (const float*)d_in[0];
  const float* pos = (const float*)d_in[1];
  // d_in[2] = batch (layout known statically, unused)
  const float* W1  = (const float*)d_in[3];
  const float* b1  = (const float*)d_in[4];
  const float* W2  = (const float*)d_in[5];
  const float* b2  = (const float*)d_in[6];
  float* dout = (float*)d_out;
  unsigned short* nbr = (unsigned short*)d_ws;
  int* cnt = (int*)((char*)d_ws + (size_t)MTOT*KNB*2);

  hipLaunchKernelGGL(k_fps,    dim3(NB),     dim3(FPS_T), 0, stream, pos, dout);
  hipLaunchKernelGGL(k_radius, dim3(MTOT/4), dim3(256),   0, stream, pos, dout, nbr, cnt);
  hipLaunchKernelGGL(k_conv,   dim3(MTOT),   dim3(128),   0, stream,
                     x, pos, W1, b1, W2, b2, nbr, cnt, dout);
}

// Round 7
// 3487.555 us; speedup vs baseline: 1.9216x; 1.0305x over previous
//
#include <hip/hip_runtime.h>
#include <stdint.h>

#define NPER 8192
#define NB 4
#define MPER 4096
#define MTOT (NB*MPER)      // 16384
#define KNB 64
#define CIN 64
#define R2C 0.04f           // f32-nearest of python 0.2*0.2 (NOT 0.2f*0.2f!)

// d_out (floats): x_out [MTOT*128] | pos_out [MTOT*3] | batch_out [MTOT]
#define POSOUT_OFF (MTOT*128)
#define BATCH_OFF  (MTOT*128 + MTOT*3)

// ws: nbr u16 [MTOT*64] @0 (2MB) | cnt i32 [MTOT] @2MB (64KB)

// ---------------------------------------------------------------- K1: FPS
// Exact lazy FPS (R6 structure) with the whole Morton-sorted cloud resident
// in dynamic LDS (Xs/Ys/Zs f32 + Os u16 = 112 KB): winner coords are 3
// same-address ds_read_b32 broadcasts instead of a global float4 (~-250cyc).
// qbuf replaced by winb u16[4096] (winner sorted-idx per iter); pos_out is
// reconstructed from LDS at the end. 1024 thr, 8 pts/thread, AABB prune
// (provably-exact skip: margin 1.2e-4 >> 5e-7 rounding), bitwise-numpy
// update ((dx*dx+dy*dy)+dz*dz, rn, no fma).
// Key = (d2bits<<26)|(rev_orig<<13)|sorted: u64 max == np.argmax first-max.
// DPP wave reduce (row_shr 1,2,4,8 + row_bcast 15,31), per-wave LDS
// atomicMax into 3-phase slot, ONE barrier/iter.
#define FPS_T 1024
#define PTS 8
#define NCELL 512

// dynamic-LDS layout (bytes)
#define OFF_XS 0
#define OFF_YS (OFF_XS + NPER*4)        // 32768
#define OFF_ZS (OFF_YS + NPER*4)        // 65536
#define OFF_OS (OFF_ZS + NPER*4)        // 98304  u16[8192]
#define OFF_WIN (OFF_OS + NPER*2)       // 114688 u16[4096]
#define OFF_HIST (OFF_WIN + MPER*2)     // 122880 u32[512]
#define OFF_SCAN (OFF_HIST + NCELL*4)   // 124928 u32[512]
#define OFF_SLOT (OFF_SCAN + NCELL*4)   // 126976 u64[3]
#define OFF_SID0 (OFF_SLOT + 24)        // 127000 u32
#define FPS_LDS  (OFF_SID0 + 8)         // 127008 B

__device__ inline unsigned morton3(unsigned ix, unsigned iy, unsigned iz) {
  unsigned m = 0;
#pragma unroll
  for (int b = 0; b < 3; ++b)
    m |= (((ix >> b) & 1u) << (3*b + 2)) | (((iy >> b) & 1u) << (3*b + 1)) |
         (((iz >> b) & 1u) << (3*b));
  return m;
}

template<int CTRL>
__device__ __forceinline__ unsigned dppmax(unsigned v) {
  unsigned t = (unsigned)__builtin_amdgcn_update_dpp(
      0, (int)v, CTRL, 0xf, 0xf, true);   // bound_ctrl: OOB lanes read 0
  return v > t ? v : t;
}
__device__ __forceinline__ unsigned wave_max_u32(unsigned v) {
  v = dppmax<0x111>(v);   // row_shr:1
  v = dppmax<0x112>(v);   // row_shr:2
  v = dppmax<0x114>(v);   // row_shr:4
  v = dppmax<0x118>(v);   // row_shr:8
  v = dppmax<0x142>(v);   // row_bcast15
  v = dppmax<0x143>(v);   // row_bcast31
  return (unsigned)__builtin_amdgcn_readlane((int)v, 63);
}

__global__ __launch_bounds__(1024) void k_fps(const float* __restrict__ pos,
                                              float* __restrict__ dout)
{
  extern __shared__ char smem[];
  float* Xs = (float*)(smem + OFF_XS);
  float* Ys = (float*)(smem + OFF_YS);
  float* Zs = (float*)(smem + OFF_ZS);
  unsigned short* Os = (unsigned short*)(smem + OFF_OS);
  unsigned short* winb = (unsigned short*)(smem + OFF_WIN);
  unsigned* hist = (unsigned*)(smem + OFF_HIST);
  unsigned* scanb = (unsigned*)(smem + OFF_SCAN);
  unsigned long long* slot3 = (unsigned long long*)(smem + OFF_SLOT);
  unsigned* sid0p = (unsigned*)(smem + OFF_SID0);

  const int b = blockIdx.x;
  const int tid = threadIdx.x;
  const float* pb = pos + (size_t)b * NPER * 3;
  float* qo = dout + POSOUT_OFF + (size_t)b * MPER * 3;

  if (tid < NCELL) hist[tid] = 0u;
  if (tid == 0) { slot3[0] = 0ull; slot3[1] = 0ull; slot3[2] = 0ull; }
  __syncthreads();

  // ---- sort pass 1: count ----
  float sxv[PTS], syv[PTS], szv[PTS];
  unsigned cellv[PTS];
#pragma unroll
  for (int k = 0; k < PTS; ++k) {
    int i = k * FPS_T + tid;
    sxv[k] = pb[i*3+0]; syv[k] = pb[i*3+1]; szv[k] = pb[i*3+2];
    unsigned ix = min(7u, (unsigned)(int)(sxv[k] * 8.0f));
    unsigned iy = min(7u, (unsigned)(int)(syv[k] * 8.0f));
    unsigned iz = min(7u, (unsigned)(int)(szv[k] * 8.0f));
    cellv[k] = morton3(ix, iy, iz);
    atomicAdd(&hist[cellv[k]], 1u);
  }
  __syncthreads();
  // ---- scan -> exclusive starts ----
  if (tid < NCELL) scanb[tid] = hist[tid];
  __syncthreads();
  for (int s = 1; s < NCELL; s <<= 1) {
    unsigned v = 0u;
    if (tid >= s && tid < NCELL) v = scanb[tid - s];
    __syncthreads();
    if (tid >= s && tid < NCELL) scanb[tid] += v;
    __syncthreads();
  }
  if (tid < NCELL) hist[tid] = scanb[tid] - hist[tid];
  __syncthreads();
  // ---- sort pass 2: scatter into LDS arrays ----
#pragma unroll
  for (int k = 0; k < PTS; ++k) {
    unsigned dst = atomicAdd(&hist[cellv[k]], 1u);
    int orig = k * FPS_T + tid;
    Xs[dst] = sxv[k]; Ys[dst] = syv[k]; Zs[dst] = szv[k];
    Os[dst] = (unsigned short)orig;
    if (orig == 0) *sid0p = dst;        // sorted position of seed point
  }
  __syncthreads();
  // ---- own 8 contiguous sorted points + AABB ----
  float X[PTS], Y[PTS], Z[PTS], D[PTS];
  unsigned RK[PTS];
  float bxlo = 3.402823466e+38f, bylo = bxlo, bzlo = bxlo;
  float bxhi = -bxlo, byhi = bxhi, bzhi = bxhi;
#pragma unroll
  for (int k = 0; k < PTS; ++k) {
    int s = tid * PTS + k;
    X[k] = Xs[s]; Y[k] = Ys[s]; Z[k] = Zs[s];
    unsigned orig = Os[s];
    RK[k] = ((unsigned)(NPER - 1 - orig) << 13) | (unsigned)s;
    D[k] = 3.402823466e+38f;
    bxlo = fminf(bxlo, X[k]); bxhi = fmaxf(bxhi, X[k]);
    bylo = fminf(bylo, Y[k]); byhi = fmaxf(byhi, Y[k]);
    bzlo = fminf(bzlo, Z[k]); bzhi = fmaxf(bzhi, Z[k]);
  }

  // ---- main loop ----
  unsigned long long tkey = 0ull, wkey = 0ull;
  float lmax = 3.402823466e+38f;
  unsigned sidx = *sid0p;
  for (int m = 1; m < MPER; ++m) {
    const float cx = Xs[sidx], cy = Ys[sidx], cz = Zs[sidx];  // broadcasts
    if (tid == 0) winb[m-1] = (unsigned short)sidx;
    if (tid == 1) slot3[(m+1) % 3] = 0ull;   // phase-safe future reset
    float ax = fmaxf(fmaxf(__fsub_rn(bxlo, cx), __fsub_rn(cx, bxhi)), 0.0f);
    float ay = fmaxf(fmaxf(__fsub_rn(bylo, cy), __fsub_rn(cy, byhi)), 0.0f);
    float az = fmaxf(fmaxf(__fsub_rn(bzlo, cz), __fsub_rn(cz, bzhi)), 0.0f);
    float lb = ax*ax + ay*ay + az*az;
    bool upd = (lb * 0.99988f) < lmax;  // margin >> rounding: skip is exact
    if (__ballot(upd) != 0ull) {        // whole wave can skip
      if (upd) {
        unsigned long long bk = 0ull;
#pragma unroll
        for (int k = 0; k < PTS; ++k) {
          float dx = __fsub_rn(X[k], cx);
          float dy = __fsub_rn(Y[k], cy);
          float dz = __fsub_rn(Z[k], cz);
          float s = __fadd_rn(__fadd_rn(__fmul_rn(dx,dx), __fmul_rn(dy,dy)),
                              __fmul_rn(dz,dz));
          float dn = fminf(D[k], s);
          D[k] = dn;
          unsigned long long kk =
            ((unsigned long long)__float_as_uint(dn) << 26) | RK[k];
          bk = (kk > bk) ? kk : bk;
        }
        tkey = bk;
        lmax = __uint_as_float((unsigned)(bk >> 26));
      }
      // exact u64-max via two u32 DPP reduces
      unsigned hi = (unsigned)(tkey >> 26);
      unsigned M = wave_max_u32(hi);
      unsigned rk = (unsigned)tkey & 0x3FFFFFFu;
      unsigned cand = (hi == M) ? (~rk & 0x3FFFFFFu) : 0u;
      unsigned C = wave_max_u32(cand);
      wkey = ((unsigned long long)M << 26) | (~C & 0x3FFFFFFu);
    }
    if ((tid & 63) == 0) atomicMax(&slot3[m % 3], wkey);
    __syncthreads();
    sidx = (unsigned)(slot3[m % 3] & 0x1FFFull);
  }
  if (tid == 0) winb[MPER-1] = (unsigned short)sidx;
  __syncthreads();
  // reconstruct pos_out from LDS (4 iters, ~12B/lane)
  for (int e = tid; e < MPER; e += FPS_T) {
    unsigned s = winb[e];
    qo[e*3+0] = Xs[s]; qo[e*3+1] = Ys[s]; qo[e*3+2] = Zs[s];
  }
}

// ------------------------------------------------- K2: radius + top-K select
// One wave per centroid. Candidates (d2<=R2) appended via ballot-prefix into
// LDS; key split into two u32 arrays (H=d2 bits, L=idx) so bitonic accesses
// are b32 (<=2 lanes/bank = conflict-free) instead of b64 (>=4-way).
// (H,L) lexicographic order == u64 key order: d2 asc, idx asc on ties ->
// exact jax top_k selection + tie-break.
#define SCAP 512
__global__ __launch_bounds__(256) void k_radius(const float* __restrict__ pos,
    float* __restrict__ dout, unsigned short* __restrict__ nbr,
    int* __restrict__ cnt)
{
  __shared__ unsigned candH[4][SCAP];
  __shared__ unsigned candL[4][SCAP];
  const int wid = threadIdx.x >> 6, lane = threadIdx.x & 63;
  const int m = blockIdx.x * 4 + wid;
  const int b = m >> 12;
  const float* pb = pos + (size_t)b * NPER * 3;
  const float* q = dout + POSOUT_OFF + (size_t)m * 3;
  const float qx = q[0], qy = q[1], qz = q[2];
  unsigned cw = 0;
  for (int it = 0; it < NPER/64; ++it) {
    int i = (it << 6) + lane;
    float dx = __fsub_rn(qx, pb[i*3+0]);
    float dy = __fsub_rn(qy, pb[i*3+1]);
    float dz = __fsub_rn(qz, pb[i*3+2]);
    float d2 = __fadd_rn(__fadd_rn(__fmul_rn(dx,dx), __fmul_rn(dy,dy)),
                         __fmul_rn(dz,dz));
    bool in = (d2 <= R2C);
    unsigned long long mk = __ballot(in);
    unsigned pre = (unsigned)__popcll(mk & ((1ull << lane) - 1ull));
    if (in) {
      unsigned slot = cw + pre;
      if (slot < SCAP) {
        candH[wid][slot] = __float_as_uint(d2);
        candL[wid][slot] = (unsigned)i;
      }
    }
    cw += (unsigned)__popcll(mk);
  }
  if (cw > SCAP) cw = SCAP;   // statistically unreachable (lambda_max ~274)
  for (int s = (int)cw + lane; s < SCAP; s += 64) {
    candH[wid][s] = 0xFFFFFFFFu; candL[wid][s] = 0xFFFFFFFFu;
  }
  __syncthreads();
  for (int k = 2; k <= SCAP; k <<= 1) {
    for (int j = k >> 1; j > 0; j >>= 1) {
#pragma unroll
      for (int s = 0; s < SCAP/128; ++s) {
        int t = lane + (s << 6);
        int e = ((t & ~(j-1)) << 1) | (t & (j-1));
        int p = e | j;
        unsigned aH = candH[wid][e], aL = candL[wid][e];
        unsigned cH = candH[wid][p], cL = candL[wid][p];
        bool agt = (aH > cH) || (aH == cH && aL > cL);
        bool asc = ((e & k) == 0);
        bool sw = asc ? agt : !agt && (aH != cH || aL != cL);
        if (sw) {
          candH[wid][e] = cH; candL[wid][e] = cL;
          candH[wid][p] = aH; candL[wid][p] = aL;
        }
      }
      __syncthreads();
    }
  }
  int kk = (int)cw; if (kk > KNB) kk = KNB;
  nbr[(size_t)m*KNB + lane] =
    (lane < kk) ? (unsigned short)(candL[wid][lane] & 0xFFFFu)
                : (unsigned short)0;
  if (lane == 0) {
    cnt[m] = kk;
    dout[BATCH_OFF + m] = (float)b;   // batch_out (buffer read as f32)
  }
}

// --------------------------------------------- K3: gather -> MLP -> max (fp32)
// One 128-thr block per centroid. featT[ch][j] (stride 68) + W1 in LDS;
// stage B: 8j x 4h register tile; h1T reuses featT buffer; W2 streamed in
// 16-row chunks through the W1 buffer; stage C: 8j x 8c tile; masked
// shuffle-max over j, write 128 outputs.
__global__ __launch_bounds__(128) void k_conv(
    const float* __restrict__ x, const float* __restrict__ pos,
    const float* __restrict__ W1, const float* __restrict__ b1,
    const float* __restrict__ W2, const float* __restrict__ b2,
    const unsigned short* __restrict__ nbr, const int* __restrict__ cntp,
    float* __restrict__ dout)
{
  __shared__ __align__(16) float bufA[68*68];   // featT then h1T (stride 68)
  __shared__ __align__(16) float bufB[68*68];   // W1 then W2 chunks (str 136)
  __shared__ unsigned short nbr_s[64];
  __shared__ float qv[3];
  __shared__ int cnt_s;
  const int t = threadIdx.x;
  const int m = blockIdx.x;
  const int b = m >> 12;
  if (t < 64) nbr_s[t] = nbr[(size_t)m*KNB + t];
  else if (t == 64) cnt_s = cntp[m];
  else if (t >= 65 && t < 68) qv[t-65] = dout[POSOUT_OFF + (size_t)m*3 + (t-65)];
  for (int e = t; e < 67*64; e += 128) {
    int ch = e >> 6, h = e & 63;
    bufB[ch*68 + h] = W1[e];
  }
  __syncthreads();
  {                                   // gather x rows -> featT rows 0..63
    const int ch = t & 63, jj = t >> 6;
    const size_t xb = (size_t)b * NPER * CIN;
    for (int j0 = 0; j0 < 64; j0 += 2) {
      int j = j0 + jj;
      int r = nbr_s[j];
      bufA[ch*68 + j] = x[xb + (size_t)r*CIN + ch];
    }
  }
  {                                   // rel -> rows 64..66
    const size_t pbb = (size_t)b * NPER * 3;
    for (int e = t; e < 192; e += 128) {
      int j = e & 63, d = e >> 6;
      int r = nbr_s[j];
      bufA[(64+d)*68 + j] = pos[pbb + (size_t)r*3 + d] - qv[d];
    }
  }
  __syncthreads();

  const int jg = t & 7, hg = t >> 3;
  const int j0 = jg << 3;
  const int h0 = hg << 2;
  float acc[4][8];
#pragma unroll
  for (int hh = 0; hh < 4; ++hh)
#pragma unroll
    for (int j = 0; j < 8; ++j) acc[hh][j] = 0.0f;
  for (int ch = 0; ch < 67; ++ch) {
    const float4 fa = *(const float4*)&bufA[ch*68 + j0];
    const float4 fb = *(const float4*)&bufA[ch*68 + j0 + 4];
    const float4 w  = *(const float4*)&bufB[ch*68 + h0];
    const float ws4[4] = {w.x, w.y, w.z, w.w};
    const float fj[8] = {fa.x, fa.y, fa.z, fa.w, fb.x, fb.y, fb.z, fb.w};
#pragma unroll
    for (int hh = 0; hh < 4; ++hh)
#pragma unroll
      for (int j = 0; j < 8; ++j)
        acc[hh][j] += ws4[hh] * fj[j];
  }
  __syncthreads();                    // featT + W1 reads complete
  {                                   // h1T = relu(acc + b1) into bufA
    const float4 bb = *(const float4*)&b1[h0];
    const float bv[4] = {bb.x, bb.y, bb.z, bb.w};
#pragma unroll
    for (int hh = 0; hh < 4; ++hh) {
      float4 o0, o1;
      o0.x = fmaxf(acc[hh][0] + bv[hh], 0.0f);
      o0.y = fmaxf(acc[hh][1] + bv[hh], 0.0f);
      o0.z = fmaxf(acc[hh][2] + bv[hh], 0.0f);
      o0.w = fmaxf(acc[hh][3] + bv[hh], 0.0f);
      o1.x = fmaxf(acc[hh][4] + bv[hh], 0.0f);
      o1.y = fmaxf(acc[hh][5] + bv[hh], 0.0f);
      o1.z = fmaxf(acc[hh][6] + bv[hh], 0.0f);
      o1.w = fmaxf(acc[hh][7] + bv[hh], 0.0f);
      *(float4*)&bufA[(h0+hh)*68 + j0] = o0;
      *(float4*)&bufA[(h0+hh)*68 + j0 + 4] = o1;
    }
  }
  const int c0 = hg << 3;             // stage C: 8j x 8c
  float acc2[8][8];                   // [c][j]
#pragma unroll
  for (int c = 0; c < 8; ++c)
#pragma unroll
    for (int j = 0; j < 8; ++j) acc2[c][j] = 0.0f;
  for (int hc = 0; hc < 64; hc += 16) {
    __syncthreads();                  // h1T ready / prior chunk consumed
    for (int e = t; e < 16*128; e += 128) {
      int hh = e >> 7, c = e & 127;
      bufB[hh*136 + c] = W2[(size_t)(hc+hh)*128 + c];
    }
    __syncthreads();
#pragma unroll
    for (int h = 0; h < 16; ++h) {
      const float4 ja = *(const float4*)&bufA[(hc+h)*68 + j0];
      const float4 jb = *(const float4*)&bufA[(hc+h)*68 + j0 + 4];
      const float4 wa = *(const float4*)&bufB[h*136 + c0];
      const float4 wb = *(const float4*)&bufB[h*136 + c0 + 4];
      const float hv[8] = {ja.x, ja.y, ja.z, ja.w, jb.x, jb.y, jb.z, jb.w};
      const float wv[8] = {wa.x, wa.y, wa.z, wa.w, wb.x, wb.y, wb.z, wb.w};
#pragma unroll
      for (int c = 0; c < 8; ++c)
#pragma unroll
        for (int j = 0; j < 8; ++j)
          acc2[c][j] += wv[c] * hv[j];
    }
  }
  const int cntv = cnt_s;
  const float4 b2a = *(const float4*)&b2[c0];
  const float4 b2b = *(const float4*)&b2[c0 + 4];
  const float bv2[8] = {b2a.x, b2a.y, b2a.z, b2a.w, b2b.x, b2b.y, b2b.z, b2b.w};
  float best[8];
#pragma unroll
  for (int c = 0; c < 8; ++c) {
    float v = -3.402823466e+38f;
#pragma unroll
    for (int j = 0; j < 8; ++j) {
      float hv = fmaxf(acc2[c][j] + bv2[c], 0.0f);
      v = (j0 + j < cntv) ? fmaxf(v, hv) : v;
    }
    best[c] = v;
  }
#pragma unroll
  for (int off = 1; off < 8; off <<= 1)
#pragma unroll
    for (int c = 0; c < 8; ++c)
      best[c] = fmaxf(best[c], __shfl_xor(best[c], off));
  if (jg == 0) {
    float4 o0 = {best[0], best[1], best[2], best[3]};
    float4 o1 = {best[4], best[5], best[6], best[7]};
    *(float4*)&dout[(size_t)m*128 + c0] = o0;
    *(float4*)&dout[(size_t)m*128 + c0 + 4] = o1;
  }
}

extern "C" void kernel_launch(void* const* d_in, const int* in_sizes, int n_in,
                              void* d_out, int out_size, void* d_ws, size_t ws_size,
                              hipStream_t stream) {
  const float* x   = (const float*)d_in[0];
  const float* pos = (const float*)d_in[1];
  // d_in[2] = batch (layout known statically, unused)
  const float* W1  = (const float*)d_in[3];
  const float* b1  = (const float*)d_in[4];
  const float* W2  = (const float*)d_in[5];
  const float* b2  = (const float*)d_in[6];
  float* dout = (float*)d_out;
  unsigned short* nbr = (unsigned short*)d_ws;
  int* cnt = (int*)((char*)d_ws + (size_t)MTOT*KNB*2);

  hipLaunchKernelGGL(k_fps,    dim3(NB),     dim3(FPS_T), FPS_LDS, stream, pos, dout);
  hipLaunchKernelGGL(k_radius, dim3(MTOT/4), dim3(256),   0, stream, pos, dout, nbr, cnt);
  hipLaunchKernelGGL(k_conv,   dim3(MTOT),   dim3(128),   0, stream,
                     x, pos, W1, b1, W2, b2, nbr, cnt, dout);
}

// Round 8
// 3353.707 us; speedup vs baseline: 1.9983x; 1.0399x over previous
//
#include <hip/hip_runtime.h>
#include <stdint.h>

#define NPER 8192
#define NB 4
#define MPER 4096
#define MTOT (NB*MPER)      // 16384
#define KNB 64
#define CIN 64
#define R2C 0.04f           // f32-nearest of python 0.2*0.2 (NOT 0.2f*0.2f!)

// d_out (floats): x_out [MTOT*128] | pos_out [MTOT*3] | batch_out [MTOT]
#define POSOUT_OFF (MTOT*128)
#define BATCH_OFF  (MTOT*128 + MTOT*3)

// ws: nbr u16 [MTOT*64] @0 (2MB) | cnt i32 [MTOT] @2MB (64KB)
// fps->radius scratch lives in the x_out region of d_out (free until k_conv):
// per cloud stride SSTR floats: SX[8192] @0 | SY @8192 | SZ @16384 |
// SO u16[8192] @24576f | CS u32[513] @28672f   (sorted by lex cell)
#define SSTR 30720

typedef float v2f __attribute__((ext_vector_type(2)));

// ---------------------------------------------------------------- K1: FPS
// Exact lazy FPS. Cloud sorted by lexicographic cell (ix<<6|iy<<3|iz, 8^3)
// into LDS (Xs/Ys/Zs/Os) AND dumped to global scratch for k_radius's cell
// culling. 1024 thr, 8 pts/thread, per-thread AABB prune (provably-exact
// skip: margin 1.2e-4 >> 5e-7 f32 rounding). Update: packed v2f pairs,
// contract(off) -> v_pk_{add,mul}_f32, IEEE rn == bitwise numpy
// ((dx*dx+dy*dy)+dz*dz). Thread key = (bd_bits<<26)|brk, brk = max RK among
// dn==bd, RK=(rev_orig<<13)|sorted -> lexicographic (d2,RK) max == np.argmax
// first-max. Wave: M = dpp_max(d2bits); single-owner fast path via
// ballot+readlane (ties essentially never); per-wave LDS atomicMax into
// 3-phase slot; ONE barrier/iter.
#define FPS_T 1024
#define PTS 8
#define NCELL 512

// dynamic-LDS layout (bytes)
#define OFF_XS 0
#define OFF_YS (OFF_XS + NPER*4)        // 32768
#define OFF_ZS (OFF_YS + NPER*4)        // 65536
#define OFF_OS (OFF_ZS + NPER*4)        // 98304  u16[8192]
#define OFF_WIN (OFF_OS + NPER*2)       // 114688 u16[4096]
#define OFF_HIST (OFF_WIN + MPER*2)     // 122880 u32[512]
#define OFF_SCAN (OFF_HIST + NCELL*4)   // 124928 u32[512]
#define OFF_SLOT (OFF_SCAN + NCELL*4)   // 126976 u64[3]
#define OFF_SID0 (OFF_SLOT + 24)        // 127000 u32
#define FPS_LDS  (OFF_SID0 + 8)         // 127008 B

template<int CTRL>
__device__ __forceinline__ unsigned dppmax(unsigned v) {
  unsigned t = (unsigned)__builtin_amdgcn_update_dpp(
      0, (int)v, CTRL, 0xf, 0xf, true);   // bound_ctrl: OOB lanes read 0
  return v > t ? v : t;
}
__device__ __forceinline__ unsigned wave_max_u32(unsigned v) {
  v = dppmax<0x111>(v);   // row_shr:1
  v = dppmax<0x112>(v);   // row_shr:2
  v = dppmax<0x114>(v);   // row_shr:4
  v = dppmax<0x118>(v);   // row_shr:8
  v = dppmax<0x142>(v);   // row_bcast15
  v = dppmax<0x143>(v);   // row_bcast31
  return (unsigned)__builtin_amdgcn_readlane((int)v, 63);
}

__global__ __launch_bounds__(1024) void k_fps(const float* __restrict__ pos,
                                              float* __restrict__ dout)
{
#pragma clang fp contract(off)
  extern __shared__ char smem[];
  float* Xs = (float*)(smem + OFF_XS);
  float* Ys = (float*)(smem + OFF_YS);
  float* Zs = (float*)(smem + OFF_ZS);
  unsigned short* Os = (unsigned short*)(smem + OFF_OS);
  unsigned short* winb = (unsigned short*)(smem + OFF_WIN);
  unsigned* hist = (unsigned*)(smem + OFF_HIST);
  unsigned* scanb = (unsigned*)(smem + OFF_SCAN);
  unsigned long long* slot3 = (unsigned long long*)(smem + OFF_SLOT);
  unsigned* sid0p = (unsigned*)(smem + OFF_SID0);

  const int b = blockIdx.x;
  const int tid = threadIdx.x;
  const float* pb = pos + (size_t)b * NPER * 3;
  float* qo = dout + POSOUT_OFF + (size_t)b * MPER * 3;
  float* scrb = dout + (size_t)b * SSTR;
  float* gSX = scrb; float* gSY = scrb + 8192; float* gSZ = scrb + 16384;
  unsigned* gSO = (unsigned*)(scrb + 24576);       // packed u16 pairs
  unsigned* gCS = (unsigned*)(scrb + 28672);       // 513 entries

  if (tid < NCELL) hist[tid] = 0u;
  if (tid == 0) { slot3[0] = 0ull; slot3[1] = 0ull; slot3[2] = 0ull; }
  __syncthreads();

  // ---- sort pass 1: count (lex cell) ----
  float sxv[PTS], syv[PTS], szv[PTS];
  unsigned cellv[PTS];
#pragma unroll
  for (int k = 0; k < PTS; ++k) {
    int i = k * FPS_T + tid;
    sxv[k] = pb[i*3+0]; syv[k] = pb[i*3+1]; szv[k] = pb[i*3+2];
    unsigned ix = min(7u, (unsigned)(int)(sxv[k] * 8.0f));
    unsigned iy = min(7u, (unsigned)(int)(syv[k] * 8.0f));
    unsigned iz = min(7u, (unsigned)(int)(szv[k] * 8.0f));
    cellv[k] = (ix << 6) | (iy << 3) | iz;
    atomicAdd(&hist[cellv[k]], 1u);
  }
  __syncthreads();
  // ---- scan -> exclusive starts; export CS to global ----
  if (tid < NCELL) scanb[tid] = hist[tid];
  __syncthreads();
  for (int s = 1; s < NCELL; s <<= 1) {
    unsigned v = 0u;
    if (tid >= s && tid < NCELL) v = scanb[tid - s];
    __syncthreads();
    if (tid >= s && tid < NCELL) scanb[tid] += v;
    __syncthreads();
  }
  if (tid < NCELL) {
    hist[tid] = scanb[tid] - hist[tid];   // exclusive start
    gCS[tid+1] = scanb[tid];              // start of cell tid+1
  }
  if (tid == 0) gCS[0] = 0u;
  __syncthreads();
  // ---- sort pass 2: scatter into LDS ----
#pragma unroll
  for (int k = 0; k < PTS; ++k) {
    unsigned dst = atomicAdd(&hist[cellv[k]], 1u);
    int orig = k * FPS_T + tid;
    Xs[dst] = sxv[k]; Ys[dst] = syv[k]; Zs[dst] = szv[k];
    Os[dst] = (unsigned short)orig;
    if (orig == 0) *sid0p = dst;
  }
  __syncthreads();
  // ---- dump sorted cloud to global scratch (for k_radius) ----
  for (int e = tid; e < NPER; e += FPS_T) {
    gSX[e] = Xs[e]; gSY[e] = Ys[e]; gSZ[e] = Zs[e];
  }
  for (int e = tid; e < NPER/2; e += FPS_T)
    gSO[e] = ((const unsigned*)Os)[e];
  // ---- own 8 contiguous sorted points + AABB ----
  v2f Xp[4], Yp[4], Zp[4], Dp[4];
  unsigned RK[PTS];
  float bxlo = 3.402823466e+38f, bylo = bxlo, bzlo = bxlo;
  float bxhi = -bxlo, byhi = bxhi, bzhi = bxhi;
#pragma unroll
  for (int k = 0; k < PTS; ++k) {
    int s = tid * PTS + k;
    float xx = Xs[s], yy = Ys[s], zz = Zs[s];
    Xp[k>>1][k&1] = xx; Yp[k>>1][k&1] = yy; Zp[k>>1][k&1] = zz;
    Dp[k>>1][k&1] = 3.402823466e+38f;
    unsigned orig = Os[s];
    RK[k] = ((unsigned)(NPER - 1 - orig) << 13) | (unsigned)s;
    bxlo = fminf(bxlo, xx); bxhi = fmaxf(bxhi, xx);
    bylo = fminf(bylo, yy); byhi = fmaxf(byhi, yy);
    bzlo = fminf(bzlo, zz); bzhi = fmaxf(bzhi, zz);
  }

  // ---- main loop ----
  unsigned long long tkey = 0ull, wkey = 0ull;
  float lmax = 3.402823466e+38f;
  unsigned sidx = *sid0p;
  for (int m = 1; m < MPER; ++m) {
    const float cx = Xs[sidx], cy = Ys[sidx], cz = Zs[sidx];  // broadcasts
    if (tid == 0) winb[m-1] = (unsigned short)sidx;
    if (tid == 1) slot3[(m+1) % 3] = 0ull;   // phase-safe future reset
    float ax = fmaxf(fmaxf(__fsub_rn(bxlo, cx), __fsub_rn(cx, bxhi)), 0.0f);
    float ay = fmaxf(fmaxf(__fsub_rn(bylo, cy), __fsub_rn(cy, byhi)), 0.0f);
    float az = fmaxf(fmaxf(__fsub_rn(bzlo, cz), __fsub_rn(cz, bzhi)), 0.0f);
    float lb = ax*ax + ay*ay + az*az;
    bool upd = (lb * 0.99988f) < lmax;  // margin >> rounding: skip is exact
    if (__ballot(upd) != 0ull) {        // whole wave can skip
      if (upd) {
        v2f cx2 = {cx, cx}, cy2 = {cy, cy}, cz2 = {cz, cz};
        v2f dnp[4];
        float bd = -1.0f;
#pragma unroll
        for (int p = 0; p < 4; ++p) {
          v2f dx = Xp[p] - cx2;
          v2f dy = Yp[p] - cy2;
          v2f dz = Zp[p] - cz2;
          v2f s = (dx*dx + dy*dy) + dz*dz;   // rn, no fma (contract off)
          v2f dn;
          dn.x = fminf(Dp[p].x, s.x);
          dn.y = fminf(Dp[p].y, s.y);
          Dp[p] = dn; dnp[p] = dn;
          bd = fmaxf(bd, fmaxf(dn.x, dn.y));
        }
        unsigned brk = 0u;
#pragma unroll
        for (int p = 0; p < 4; ++p) {
          brk = (dnp[p].x == bd) ? max(brk, RK[2*p])   : brk;
          brk = (dnp[p].y == bd) ? max(brk, RK[2*p+1]) : brk;
        }
        tkey = ((unsigned long long)__float_as_uint(bd) << 26) | brk;
        lmax = bd;
      }
      unsigned hi = (unsigned)(tkey >> 26);
      unsigned M = wave_max_u32(hi);
      unsigned rk = (unsigned)tkey & 0x3FFFFFFu;
      unsigned long long msk = __ballot(hi == M);
      unsigned lo;
      if (__popcll(msk) == 1) {          // sole owner (the ~always case)
        int ln = (int)__builtin_ctzll(msk);
        lo = (unsigned)__builtin_amdgcn_readlane((int)rk, ln);
      } else {                           // exact d2 tie: max RK = min orig
        lo = wave_max_u32((hi == M) ? rk : 0u);
      }
      wkey = ((unsigned long long)M << 26) | lo;
    }
    if ((tid & 63) == 0) atomicMax(&slot3[m % 3], wkey);
    __syncthreads();
    sidx = (unsigned)(slot3[m % 3] & 0x1FFFull);
  }
  if (tid == 0) winb[MPER-1] = (unsigned short)sidx;
  __syncthreads();
  // reconstruct pos_out from LDS
  for (int e = tid; e < MPER; e += FPS_T) {
    unsigned s = winb[e];
    qo[e*3+0] = Xs[s]; qo[e*3+1] = Ys[s]; qo[e*3+2] = Zs[s];
  }
}

// ------------------------------------------------- K2: radius + top-K select
// One wave per centroid. Cell-culled: only the +-2-cell block around the
// centroid's cell is scanned (exact: R=0.2 < 2*0.125). 25 (ix,iy) segments,
// each a contiguous iz-run in the lex-sorted scratch; bounds prefetched
// lane-parallel then readlane'd. Candidates (d2<=R2) appended via
// ballot-prefix; keys (H=d2 bits, L=orig idx) sorted by 512-bitonic ->
// selection set + lower-index tie-break bitwise equal to jax top_k.
#define SCAP 512
__global__ __launch_bounds__(256) void k_radius(const float* __restrict__ pos,
    float* __restrict__ dout, unsigned short* __restrict__ nbr,
    int* __restrict__ cnt)
{
  __shared__ unsigned candH[4][SCAP];
  __shared__ unsigned candL[4][SCAP];
  const int wid = threadIdx.x >> 6, lane = threadIdx.x & 63;
  const int m = blockIdx.x * 4 + wid;
  const int b = m >> 12;
  const float* scrb = dout + (size_t)b * SSTR;
  const float* SX = scrb;
  const float* SY = scrb + 8192;
  const float* SZ = scrb + 16384;
  const unsigned short* SO = (const unsigned short*)(scrb + 24576);
  const unsigned* CS = (const unsigned*)(scrb + 28672);
  const float* q = dout + POSOUT_OFF + (size_t)m * 3;
  const float qx = q[0], qy = q[1], qz = q[2];
  const int ixc = min(7, (int)(qx * 8.0f));
  const int iyc = min(7, (int)(qy * 8.0f));
  const int izc = min(7, (int)(qz * 8.0f));
  const int izlo = max(izc-2, 0), izhi = min(izc+2, 7);
  // lanes 0..24 prefetch segment bounds
  unsigned s0v = 0u, s1v = 0u;
  {
    int ix = ixc + lane / 5 - 2;
    int iy = iyc + lane % 5 - 2;
    if (lane < 25 && ix >= 0 && ix < 8 && iy >= 0 && iy < 8) {
      int cb = (ix << 6) | (iy << 3);
      s0v = CS[cb + izlo];
      s1v = CS[cb + izhi + 1];
    }
  }
  unsigned cw = 0;
  for (int seg = 0; seg < 25; ++seg) {
    unsigned s0 = (unsigned)__builtin_amdgcn_readlane((int)s0v, seg);
    unsigned s1 = (unsigned)__builtin_amdgcn_readlane((int)s1v, seg);
    for (unsigned i0 = s0; i0 < s1; i0 += 64) {
      unsigned i = i0 + (unsigned)lane;     // OOB lanes read harmless bytes
      float dx = __fsub_rn(qx, SX[i]);
      float dy = __fsub_rn(qy, SY[i]);
      float dz = __fsub_rn(qz, SZ[i]);
      float d2 = __fadd_rn(__fadd_rn(__fmul_rn(dx,dx), __fmul_rn(dy,dy)),
                           __fmul_rn(dz,dz));
      bool in = (i < s1) && (d2 <= R2C);
      unsigned long long mk = __ballot(in);
      unsigned pre = (unsigned)__popcll(mk & ((1ull << lane) - 1ull));
      if (in) {
        unsigned slot = cw + pre;
        if (slot < SCAP) {
          candH[wid][slot] = __float_as_uint(d2);
          candL[wid][slot] = (unsigned)SO[i];
        }
      }
      cw += (unsigned)__popcll(mk);
    }
  }
  if (cw > SCAP) cw = SCAP;   // statistically unreachable (lambda_max ~274)
  for (int s = (int)cw + lane; s < SCAP; s += 64) {
    candH[wid][s] = 0xFFFFFFFFu; candL[wid][s] = 0xFFFFFFFFu;
  }
  __syncthreads();
  for (int k = 2; k <= SCAP; k <<= 1) {
    for (int j = k >> 1; j > 0; j >>= 1) {
#pragma unroll
      for (int s = 0; s < SCAP/128; ++s) {
        int t = lane + (s << 6);
        int e = ((t & ~(j-1)) << 1) | (t & (j-1));
        int p = e | j;
        unsigned aH = candH[wid][e], aL = candL[wid][e];
        unsigned cH = candH[wid][p], cL = candL[wid][p];
        bool agt = (aH > cH) || (aH == cH && aL > cL);
        bool asc = ((e & k) == 0);
        bool sw = asc ? agt : !agt && (aH != cH || aL != cL);
        if (sw) {
          candH[wid][e] = cH; candL[wid][e] = cL;
          candH[wid][p] = aH; candL[wid][p] = aL;
        }
      }
      __syncthreads();
    }
  }
  int kk = (int)cw; if (kk > KNB) kk = KNB;
  nbr[(size_t)m*KNB + lane] =
    (lane < kk) ? (unsigned short)(candL[wid][lane] & 0xFFFFu)
                : (unsigned short)0;
  if (lane == 0) {
    cnt[m] = kk;
    dout[BATCH_OFF + m] = (float)b;   // batch_out (buffer read as f32)
  }
}

// --------------------------------------------- K3: gather -> MLP -> max (fp32)
// One 128-thr block per centroid. featT[ch][j] (stride 68) + W1 in LDS;
// stage B: 8j x 4h register tile; h1T reuses featT buffer; W2 streamed in
// 16-row chunks through the W1 buffer; stage C: 8j x 8c tile; masked
// shuffle-max over j, write 128 outputs.
__global__ __launch_bounds__(128) void k_conv(
    const float* __restrict__ x, const float* __restrict__ pos,
    const float* __restrict__ W1, const float* __restrict__ b1,
    const float* __restrict__ W2, const float* __restrict__ b2,
    const unsigned short* __restrict__ nbr, const int* __restrict__ cntp,
    float* __restrict__ dout)
{
  __shared__ __align__(16) float bufA[68*68];   // featT then h1T (stride 68)
  __shared__ __align__(16) float bufB[68*68];   // W1 then W2 chunks (str 136)
  __shared__ unsigned short nbr_s[64];
  __shared__ float qv[3];
  __shared__ int cnt_s;
  const int t = threadIdx.x;
  const int m = blockIdx.x;
  const int b = m >> 12;
  if (t < 64) nbr_s[t] = nbr[(size_t)m*KNB + t];
  else if (t == 64) cnt_s = cntp[m];
  else if (t >= 65 && t < 68) qv[t-65] = dout[POSOUT_OFF + (size_t)m*3 + (t-65)];
  for (int e = t; e < 67*64; e += 128) {
    int ch = e >> 6, h = e & 63;
    bufB[ch*68 + h] = W1[e];
  }
  __syncthreads();
  {                                   // gather x rows -> featT rows 0..63
    const int ch = t & 63, jj = t >> 6;
    const size_t xb = (size_t)b * NPER * CIN;
    for (int j0 = 0; j0 < 64; j0 += 2) {
      int j = j0 + jj;
      int r = nbr_s[j];
      bufA[ch*68 + j] = x[xb + (size_t)r*CIN + ch];
    }
  }
  {                                   // rel -> rows 64..66
    const size_t pbb = (size_t)b * NPER * 3;
    for (int e = t; e < 192; e += 128) {
      int j = e & 63, d = e >> 6;
      int r = nbr_s[j];
      bufA[(64+d)*68 + j] = pos[pbb + (size_t)r*3 + d] - qv[d];
    }
  }
  __syncthreads();

  const int jg = t & 7, hg = t >> 3;
  const int j0 = jg << 3;
  const int h0 = hg << 2;
  float acc[4][8];
#pragma unroll
  for (int hh = 0; hh < 4; ++hh)
#pragma unroll
    for (int j = 0; j < 8; ++j) acc[hh][j] = 0.0f;
  for (int ch = 0; ch < 67; ++ch) {
    const float4 fa = *(const float4*)&bufA[ch*68 + j0];
    const float4 fb = *(const float4*)&bufA[ch*68 + j0 + 4];
    const float4 w  = *(const float4*)&bufB[ch*68 + h0];
    const float ws4[4] = {w.x, w.y, w.z, w.w};
    const float fj[8] = {fa.x, fa.y, fa.z, fa.w, fb.x, fb.y, fb.z, fb.w};
#pragma unroll
    for (int hh = 0; hh < 4; ++hh)
#pragma unroll
      for (int j = 0; j < 8; ++j)
        acc[hh][j] += ws4[hh] * fj[j];
  }
  __syncthreads();                    // featT + W1 reads complete
  {                                   // h1T = relu(acc + b1) into bufA
    const float4 bb = *(const float4*)&b1[h0];
    const float bv[4] = {bb.x, bb.y, bb.z, bb.w};
#pragma unroll
    for (int hh = 0; hh < 4; ++hh) {
      float4 o0, o1;
      o0.x = fmaxf(acc[hh][0] + bv[hh], 0.0f);
      o0.y = fmaxf(acc[hh][1] + bv[hh], 0.0f);
      o0.z = fmaxf(acc[hh][2] + bv[hh], 0.0f);
      o0.w = fmaxf(acc[hh][3] + bv[hh], 0.0f);
      o1.x = fmaxf(acc[hh][4] + bv[hh], 0.0f);
      o1.y = fmaxf(acc[hh][5] + bv[hh], 0.0f);
      o1.z = fmaxf(acc[hh][6] + bv[hh], 0.0f);
      o1.w = fmaxf(acc[hh][7] + bv[hh], 0.0f);
      *(float4*)&bufA[(h0+hh)*68 + j0] = o0;
      *(float4*)&bufA[(h0+hh)*68 + j0 + 4] = o1;
    }
  }
  const int c0 = hg << 3;             // stage C: 8j x 8c
  float acc2[8][8];                   // [c][j]
#pragma unroll
  for (int c = 0; c < 8; ++c)
#pragma unroll
    for (int j = 0; j < 8; ++j) acc2[c][j] = 0.0f;
  for (int hc = 0; hc < 64; hc += 16) {
    __syncthreads();                  // h1T ready / prior chunk consumed
    for (int e = t; e < 16*128; e += 128) {
      int hh = e >> 7, c = e & 127;
      bufB[hh*136 + c] = W2[(size_t)(hc+hh)*128 + c];
    }
    __syncthreads();
#pragma unroll
    for (int h = 0; h < 16; ++h) {
      const float4 ja = *(const float4*)&bufA[(hc+h)*68 + j0];
      const float4 jb = *(const float4*)&bufA[(hc+h)*68 + j0 + 4];
      const float4 wa = *(const float4*)&bufB[h*136 + c0];
      const float4 wb = *(const float4*)&bufB[h*136 + c0 + 4];
      const float hv[8] = {ja.x, ja.y, ja.z, ja.w, jb.x, jb.y, jb.z, jb.w};
      const float wv[8] = {wa.x, wa.y, wa.z, wa.w, wb.x, wb.y, wb.z, wb.w};
#pragma unroll
      for (int c = 0; c < 8; ++c)
#pragma unroll
        for (int j = 0; j < 8; ++j)
          acc2[c][j] += wv[c] * hv[j];
    }
  }
  const int cntv = cnt_s;
  const float4 b2a = *(const float4*)&b2[c0];
  const float4 b2b = *(const float4*)&b2[c0 + 4];
  const float bv2[8] = {b2a.x, b2a.y, b2a.z, b2a.w, b2b.x, b2b.y, b2b.z, b2b.w};
  float best[8];
#pragma unroll
  for (int c = 0; c < 8; ++c) {
    float v = -3.402823466e+38f;
#pragma unroll
    for (int j = 0; j < 8; ++j) {
      float hv = fmaxf(acc2[c][j] + bv2[c], 0.0f);
      v = (j0 + j < cntv) ? fmaxf(v, hv) : v;
    }
    best[c] = v;
  }
#pragma unroll
  for (int off = 1; off < 8; off <<= 1)
#pragma unroll
    for (int c = 0; c < 8; ++c)
      best[c] = fmaxf(best[c], __shfl_xor(best[c], off));
  if (jg == 0) {
    float4 o0 = {best[0], best[1], best[2], best[3]};
    float4 o1 = {best[4], best[5], best[6], best[7]};
    *(float4*)&dout[(size_t)m*128 + c0] = o0;
    *(float4*)&dout[(size_t)m*128 + c0 + 4] = o1;
  }
}

extern "C" void kernel_launch(void* const* d_in, const int* in_sizes, int n_in,
                              void* d_out, int out_size, void* d_ws, size_t ws_size,
                              hipStream_t stream) {
  const float* x   = (const float*)d_in[0];
  const float* pos = (const float*)d_in[1];
  // d_in[2] = batch (layout known statically, unused)
  const float* W1  = (const float*)d_in[3];
  const float* b1  = (const float*)d_in[4];
  const float* W2  = (const float*)d_in[5];
  const float* b2  = (const float*)d_in[6];
  float* dout = (float*)d_out;
  unsigned short* nbr = (unsigned short*)d_ws;
  int* cnt = (int*)((char*)d_ws + (size_t)MTOT*KNB*2);

  hipLaunchKernelGGL(k_fps,    dim3(NB),     dim3(FPS_T), FPS_LDS, stream, pos, dout);
  hipLaunchKernelGGL(k_radius, dim3(MTOT/4), dim3(256),   0, stream, pos, dout, nbr, cnt);
  hipLaunchKernelGGL(k_conv,   dim3(MTOT),   dim3(128),   0, stream,
                     x, pos, W1, b1, W2, b2, nbr, cnt, dout);
}